// Round 3
// baseline (697.519 us; speedup 1.0000x reference)
//
#include <hip/hip_runtime.h>
#include <hip/hip_bf16.h>
#include <stdint.h>

// GnnActor fused deepset actor. INPUTS/OUTPUTS ARE FLOAT32 (reference dtype).
// v4 (decouple streaming from compute):
//  - prep kernel: streams ef (302 MB) at full BW computing per-(b,node) segmax,
//    writes bf16 g_segb (19 MB); also bf16-casts obs/iso/isof (32 MB) and
//    transposes weights. One launch, no barriers in the streaming paths.
//  - node_kernel: A-fragments read DIRECTLY from L3-resident bf16 arrays
//    (no LDS A-staging, no f32->bf16 in hot loop), B direct from L2 weights.
//    One block = 16 batch rows x ALL 12 nodes -> pool finishes in-register ->
//    rho GEMM + heads fused in the same block. g_pool2 and rho_heads deleted.
//  - no min-waves launch_bounds clamp (v3 regression: VGPR 64 killed ILP).
// Scratch in module __device__ arrays (no d_ws use; graph-safe).

#define Bsz   8192
#define OBSW  1216      // 64 + 9*128
#define NH    256

typedef unsigned short u16;
typedef unsigned int   u32;

using bf16x8 = __attribute__((ext_vector_type(8))) short;
using f32x4  = __attribute__((ext_vector_type(4))) float;

// ---- module-scope scratch (~52 MB .bss) ----
__device__ __attribute__((aligned(16))) u16 g_W1t[256 * 320];   // bf16(W1)^T
__device__ __attribute__((aligned(16))) u16 g_W2t[256 * 256];   // bf16(W2)^T
__device__ __attribute__((aligned(16))) u16 g_Rt [256 * 256];   // bf16(Wrho)^T
__device__ __attribute__((aligned(16))) u16 g_Wcat[64 * 256];   // [Wm^T ; Ws^T]
__device__ __attribute__((aligned(16))) u16 g_obsb[(size_t)Bsz * OBSW];     // bf16(obs)
__device__ __attribute__((aligned(16))) u16 g_segb[(size_t)Bsz * 9 * 128];  // bf16 segmax
__device__ __attribute__((aligned(16))) u16 g_isob[(size_t)Bsz * 3 * 128];  // bf16(iso)
__device__ __attribute__((aligned(16))) u16 g_isofb[(size_t)Bsz * 3 * 128]; // bf16(isof)

__device__ __forceinline__ u16 f2bf(float f) {
  union { float f; u32 i; } v; v.f = f;
  u32 x = v.i;
  x += 0x7fffu + ((x >> 16) & 1u);   // RNE; values here are finite
  return (u16)(x >> 16);
}
__device__ __forceinline__ uint4 pack8(const float* f) {
  uint4 o;
  o.x = (u32)f2bf(f[0]) | ((u32)f2bf(f[1]) << 16);
  o.y = (u32)f2bf(f[2]) | ((u32)f2bf(f[3]) << 16);
  o.z = (u32)f2bf(f[4]) | ((u32)f2bf(f[5]) << 16);
  o.w = (u32)f2bf(f[6]) | ((u32)f2bf(f[7]) << 16);
  return o;
}
__device__ __forceinline__ void load8f(const float* p, float* f) {
  *(float4*)(f)     = *(const float4*)(p);
  *(float4*)(f + 4) = *(const float4*)(p + 4);
}

// ---------------- prep: segmax + casts + weight transpose (one launch) ---------
#define SEGB 8192                 // one block per batch row
#define OBSB 4864                 // 8192*1216/(256*8)
#define ISOB 1536                 // 8192*384/(256*8)
// grid = SEGB + OBSB + 2*ISOB + 224 = 16352

__global__ __launch_bounds__(256)
void prep(const float* __restrict__ obs, const float* __restrict__ ef,
          const float* __restrict__ iso, const float* __restrict__ isof,
          const float* __restrict__ W1, const float* __restrict__ W2,
          const float* __restrict__ Wr, const float* __restrict__ Wm,
          const float* __restrict__ Wsg) {
  __shared__ u16 tile[32][33];
  int bx = blockIdx.x;
  const int tid = threadIdx.x;
  if (bx < SEGB) {
    // segmax: edge e = n + 9j feeds node n. thread (g,dq): node g (+node 8 if g==0)
    const int b = bx, dq = (tid & 31) * 4, g = tid >> 5;
    const int cnt = (g == 0) ? 2 : 1;
    for (int r = 0; r < cnt; r++) {
      const int n = (r == 0) ? g : 8;
      const float* base = ef + ((size_t)b * 72 + n) * 128 + dq;
      float4 m = *(const float4*)base;
      #pragma unroll
      for (int j = 1; j < 8; j++) {
        float4 w = *(const float4*)(base + (size_t)j * 1152);
        m.x = fmaxf(m.x, w.x); m.y = fmaxf(m.y, w.y);
        m.z = fmaxf(m.z, w.z); m.w = fmaxf(m.w, w.w);
      }
      ushort4 o = { f2bf(m.x), f2bf(m.y), f2bf(m.z), f2bf(m.w) };
      *(ushort4*)(g_segb + ((size_t)b * 9 + n) * 128 + dq) = o;
    }
  } else if (bx < SEGB + OBSB) {
    size_t i = ((size_t)(bx - SEGB) * 256 + tid) * 8;
    float f[8]; load8f(obs + i, f);
    *(uint4*)(g_obsb + i) = pack8(f);
  } else if (bx < SEGB + OBSB + ISOB) {
    size_t i = ((size_t)(bx - SEGB - OBSB) * 256 + tid) * 8;
    float f[8]; load8f(iso + i, f);
    *(uint4*)(g_isob + i) = pack8(f);
  } else if (bx < SEGB + OBSB + 2 * ISOB) {
    size_t i = ((size_t)(bx - SEGB - OBSB - ISOB) * 256 + tid) * 8;
    float f[8]; load8f(isof + i, f);
    *(uint4*)(g_isofb + i) = pack8(f);
  } else {
    // weight transpose+cast: f32 in[K][N] -> bf16 out[N][K]
    bx -= SEGB + OBSB + 2 * ISOB;
    const float* in; u16* out; int K, N, row_off = 0, k0, n0;
    if (bx < 80)       { in = W1;  out = g_W1t;  K = 320; N = 256; k0 = (bx % 10) * 32; n0 = (bx / 10) * 32; }
    else if (bx < 144) { bx -= 80;  in = W2;  out = g_W2t;  K = 256; N = 256; k0 = (bx & 7) * 32; n0 = (bx >> 3) * 32; }
    else if (bx < 208) { bx -= 144; in = Wr;  out = g_Rt;   K = 256; N = 256; k0 = (bx & 7) * 32; n0 = (bx >> 3) * 32; }
    else if (bx < 216) { bx -= 208; in = Wm;  out = g_Wcat; K = 256; N = 32;  k0 = bx * 32; n0 = 0; }
    else               { bx -= 216; in = Wsg; out = g_Wcat; K = 256; N = 32;  k0 = bx * 32; n0 = 0; row_off = 32; }
    int c = tid & 31, r0 = tid >> 5;
    #pragma unroll
    for (int i = 0; i < 4; i++) {
      int r = r0 + i * 8;
      tile[r][c] = f2bf(in[(size_t)(k0 + r) * N + (n0 + c)]);
    }
    __syncthreads();
    #pragma unroll
    for (int i = 0; i < 4; i++) {
      int r = r0 + i * 8;
      out[(size_t)(n0 + r + row_off) * K + (k0 + c)] = tile[c][r];
    }
  }
}

// ---------------- fused node + rho + heads kernel ------------------------------
// grid = Bsz/16. Block: 16 rows x 12 nodes -> pool in regs -> GEMM3 -> heads.
__global__ __launch_bounds__(256)
void node_kernel(const float* __restrict__ b1, const float* __restrict__ b2,
                 const float* __restrict__ br, const float* __restrict__ bm,
                 const float* __restrict__ bs, float* __restrict__ out) {
  __shared__ __attribute__((aligned(16))) u16 Ht[16][264];  // 16x256, pad->2-way
  const int b0 = blockIdx.x * 16;
  const int tid = threadIdx.x;
  const int wave = tid >> 6, lane = tid & 63;
  const int nw = wave * 64, lrow = lane & 15, quad = lane >> 4;
  const size_t ar = (size_t)(b0 + lrow);          // A-row this lane reads
  const u16* obsrow = g_obsb + ar * OBSW;

  float bv1[4], bv2[4];
  #pragma unroll
  for (int nb = 0; nb < 4; nb++) {
    int col = nw + nb * 16 + lrow;
    bv1[nb] = b1[col]; bv2[nb] = b2[col];
  }

  const f32x4 vzero = {0.f, 0.f, 0.f, 0.f};
  f32x4 pool[4];
  #pragma unroll
  for (int b = 0; b < 4; b++) pool[b] = vzero;

  for (int n = 0; n < 12; n++) {
    // srcA + kk valid for kk in [64,192); srcS + kk valid for kk in [192,320)
    const u16* srcA = (n < 9) ? obsrow + n * 128
                              : g_isob  + (ar * 3 + (n - 9)) * 128 - 64;
    const u16* srcS = (n < 9) ? g_segb  + (ar * 9 + n) * 128 - 192
                              : g_isofb + (ar * 3 + (n - 9)) * 128 - 192;
    f32x4 acc[4];
    #pragma unroll
    for (int b = 0; b < 4; b++) acc[b] = vzero;

    // ---- GEMM1: K=320, A direct from global bf16 (L1/L3), B from L2 --------
    #pragma unroll
    for (int kc = 0; kc < 10; kc++) {
      const int kk = kc * 32 + quad * 8;
      const u16* ap = (kc < 2) ? obsrow + kk : (kc < 6) ? srcA + kk : srcS + kk;
      bf16x8 af = *(const bf16x8*)ap;
      #pragma unroll
      for (int nb = 0; nb < 4; nb++) {
        bf16x8 bq = *(const bf16x8*)(g_W1t + (size_t)(nw + nb * 16 + lrow) * 320 + kk);
        acc[nb] = __builtin_amdgcn_mfma_f32_16x16x32_bf16(af, bq, acc[nb], 0, 0, 0);
      }
    }

    __syncthreads();   // previous node's Ht reads complete (no-op first iter)
    // epilogue 1: Ht = bf16(relu(acc + b1))  (D: row=quad*4+i, col)
    #pragma unroll
    for (int nb = 0; nb < 4; nb++) {
      int col = nw + nb * 16 + lrow;
      #pragma unroll
      for (int i = 0; i < 4; i++)
        Ht[quad * 4 + i][col] = f2bf(fmaxf(acc[nb][i] + bv1[nb], 0.f));
    }
    __syncthreads();   // Ht(n) ready

    #pragma unroll
    for (int b = 0; b < 4; b++) acc[b] = vzero;
    // ---- GEMM2: K=256, A from Ht (LDS), B from L2 --------------------------
    #pragma unroll
    for (int kc = 0; kc < 8; kc++) {
      const int kk = kc * 32 + quad * 8;
      bf16x8 af = *(const bf16x8*)(&Ht[lrow][kk]);
      #pragma unroll
      for (int nb = 0; nb < 4; nb++) {
        bf16x8 bq = *(const bf16x8*)(g_W2t + (size_t)(nw + nb * 16 + lrow) * 256 + kk);
        acc[nb] = __builtin_amdgcn_mfma_f32_16x16x32_bf16(af, bq, acc[nb], 0, 0, 0);
      }
    }
    // epilogue 2: pool += relu(acc + b2)
    #pragma unroll
    for (int nb = 0; nb < 4; nb++)
      #pragma unroll
      for (int i = 0; i < 4; i++)
        pool[nb][i] += fmaxf(acc[nb][i] + bv2[nb], 0.f);
  }

  // ---- rho: pooled -> bf16 A-tile (reuse Ht) -> GEMM3(relu,br) -------------
  __syncthreads();   // last GEMM2's Ht reads done
  #pragma unroll
  for (int nb = 0; nb < 4; nb++) {
    int col = nw + nb * 16 + lrow;
    #pragma unroll
    for (int i = 0; i < 4; i++)
      Ht[quad * 4 + i][col] = f2bf(pool[nb][i]);
  }
  __syncthreads();

  f32x4 acc[4];
  #pragma unroll
  for (int b = 0; b < 4; b++) acc[b] = vzero;
  #pragma unroll
  for (int kc = 0; kc < 8; kc++) {
    const int kk = kc * 32 + quad * 8;
    bf16x8 af = *(const bf16x8*)(&Ht[lrow][kk]);
    #pragma unroll
    for (int nb = 0; nb < 4; nb++) {
      bf16x8 bq = *(const bf16x8*)(g_Rt + (size_t)(nw + nb * 16 + lrow) * 256 + kk);
      acc[nb] = __builtin_amdgcn_mfma_f32_16x16x32_bf16(af, bq, acc[nb], 0, 0, 0);
    }
  }
  __syncthreads();   // Ht reads done
  #pragma unroll
  for (int nb = 0; nb < 4; nb++) {
    int col = nw + nb * 16 + lrow;
    float bv = br[col];
    #pragma unroll
    for (int i = 0; i < 4; i++)
      Ht[quad * 4 + i][col] = f2bf(fmaxf(acc[nb][i] + bv, 0.f));
  }
  __syncthreads();   // r visible

  // ---- heads: N=64 (mean|log_std); wave w owns 16-col tile w ---------------
  f32x4 acc2 = vzero;
  #pragma unroll
  for (int kc = 0; kc < 8; kc++) {
    const int kk = kc * 32 + quad * 8;
    bf16x8 af = *(const bf16x8*)(&Ht[lrow][kk]);
    bf16x8 bq = *(const bf16x8*)(g_Wcat + (size_t)(wave * 16 + lrow) * 256 + kk);
    acc2 = __builtin_amdgcn_mfma_f32_16x16x32_bf16(af, bq, acc2, 0, 0, 0);
  }
  int j = wave * 16 + lrow;
  #pragma unroll
  for (int i = 0; i < 4; i++) {
    int b = b0 + quad * 4 + i;
    if (j < 32) {
      out[(size_t)b * 32 + j] = acc2[i] + bm[j];
    } else {
      float v = acc2[i] + bs[j - 32];
      v = fminf(fmaxf(v, -20.f), 2.f);
      out[(size_t)Bsz * 32 + (size_t)b * 32 + (j - 32)] = v;
    }
  }
}

extern "C" void kernel_launch(void* const* d_in, const int* in_sizes, int n_in,
                              void* d_out, int out_size, void* d_ws, size_t ws_size,
                              hipStream_t stream) {
  const float* obs  = (const float*)d_in[0];
  const float* ef   = (const float*)d_in[1];
  // d_in[2] = edges_to (int32): tile(arange(9),8) -> edge e feeds node e%9
  const float* iso  = (const float*)d_in[3];
  const float* isof = (const float*)d_in[4];
  const float* W1   = (const float*)d_in[5];
  const float* b1   = (const float*)d_in[6];
  const float* W2   = (const float*)d_in[7];
  const float* b2   = (const float*)d_in[8];
  const float* Wr   = (const float*)d_in[9];
  const float* br   = (const float*)d_in[10];
  const float* Wm   = (const float*)d_in[11];
  const float* bm   = (const float*)d_in[12];
  const float* Wsg  = (const float*)d_in[13];
  const float* bs   = (const float*)d_in[14];
  float* out = (float*)d_out;
  (void)d_ws; (void)ws_size;

  prep<<<SEGB + OBSB + 2 * ISOB + 224, 256, 0, stream>>>(
      obs, ef, iso, isof, W1, W2, Wr, Wm, Wsg);
  node_kernel<<<Bsz / 16, 256, 0, stream>>>(b1, b2, br, bm, bs, out);
}

// Round 4
// 563.259 us; speedup vs baseline: 1.2384x; 1.2384x over previous
//
#include <hip/hip_runtime.h>
#include <hip/hip_bf16.h>
#include <stdint.h>

// GnnActor fused deepset actor. INPUTS/OUTPUTS ARE FLOAT32 (reference dtype).
// v5 (register-resident weights):
//  - node_kernel waves hold their W1^T (160 VGPR) and W2^T (128 VGPR) MFMA
//    B-fragments RESIDENT in the unified VGPR/AGPR file for the whole kernel.
//    Loaded once per block; the 12-node loop has ZERO B loads (was 1.7 GB of
//    latency-exposed L2 re-reads). Per node: 10 A-frag loads (L1/L3) + 72 MFMA
//    + LDS Ht exchange. launch_bounds(256,1) -> up to 512 regs, 1 wave/SIMD.
//  - grid 256 (1 block/CU); each block processes 2 batch-tiles of 16 rows to
//    amortize the weight prologue. rho+heads fused per tile as in v4.
//  - prep unchanged except node-8 segmax spread across lane groups by (b&7).
// Scratch in module __device__ arrays (no d_ws use; graph-safe).

#define Bsz   8192
#define OBSW  1216      // 64 + 9*128
#define NH    256

typedef unsigned short u16;
typedef unsigned int   u32;

using bf16x8 = __attribute__((ext_vector_type(8))) short;
using f32x4  = __attribute__((ext_vector_type(4))) float;

// ---- module-scope scratch (~52 MB .bss) ----
__device__ __attribute__((aligned(16))) u16 g_W1t[256 * 320];   // bf16(W1)^T
__device__ __attribute__((aligned(16))) u16 g_W2t[256 * 256];   // bf16(W2)^T
__device__ __attribute__((aligned(16))) u16 g_Rt [256 * 256];   // bf16(Wrho)^T
__device__ __attribute__((aligned(16))) u16 g_Wcat[64 * 256];   // [Wm^T ; Ws^T]
__device__ __attribute__((aligned(16))) u16 g_obsb[(size_t)Bsz * OBSW];     // bf16(obs)
__device__ __attribute__((aligned(16))) u16 g_segb[(size_t)Bsz * 9 * 128];  // bf16 segmax
__device__ __attribute__((aligned(16))) u16 g_isob[(size_t)Bsz * 3 * 128];  // bf16(iso)
__device__ __attribute__((aligned(16))) u16 g_isofb[(size_t)Bsz * 3 * 128]; // bf16(isof)

__device__ __forceinline__ u16 f2bf(float f) {
  union { float f; u32 i; } v; v.f = f;
  u32 x = v.i;
  x += 0x7fffu + ((x >> 16) & 1u);   // RNE; values here are finite
  return (u16)(x >> 16);
}
__device__ __forceinline__ uint4 pack8(const float* f) {
  uint4 o;
  o.x = (u32)f2bf(f[0]) | ((u32)f2bf(f[1]) << 16);
  o.y = (u32)f2bf(f[2]) | ((u32)f2bf(f[3]) << 16);
  o.z = (u32)f2bf(f[4]) | ((u32)f2bf(f[5]) << 16);
  o.w = (u32)f2bf(f[6]) | ((u32)f2bf(f[7]) << 16);
  return o;
}
__device__ __forceinline__ void load8f(const float* p, float* f) {
  *(float4*)(f)     = *(const float4*)(p);
  *(float4*)(f + 4) = *(const float4*)(p + 4);
}

// ---------------- prep: segmax + casts + weight transpose (one launch) ---------
#define SEGB 8192                 // one block per batch row
#define OBSB 4864                 // 8192*1216/(256*8)
#define ISOB 1536                 // 8192*384/(256*8)
// grid = SEGB + OBSB + 2*ISOB + 224 = 16352

__global__ __launch_bounds__(256)
void prep(const float* __restrict__ obs, const float* __restrict__ ef,
          const float* __restrict__ iso, const float* __restrict__ isof,
          const float* __restrict__ W1, const float* __restrict__ W2,
          const float* __restrict__ Wr, const float* __restrict__ Wm,
          const float* __restrict__ Wsg) {
  __shared__ u16 tile[32][33];
  int bx = blockIdx.x;
  const int tid = threadIdx.x;
  if (bx < SEGB) {
    // segmax: edge e = n + 9j feeds node n. group g does node g; node 8 done by
    // group (b&7) so the extra row rotates across waves.
    const int b = bx, dq = (tid & 31) * 4, g = tid >> 5;
    const int cnt = (g == (b & 7)) ? 2 : 1;
    for (int r = 0; r < cnt; r++) {
      const int n = (r == 0) ? g : 8;
      const float* base = ef + ((size_t)b * 72 + n) * 128 + dq;
      float4 m = *(const float4*)base;
      #pragma unroll
      for (int j = 1; j < 8; j++) {
        float4 w = *(const float4*)(base + (size_t)j * 1152);
        m.x = fmaxf(m.x, w.x); m.y = fmaxf(m.y, w.y);
        m.z = fmaxf(m.z, w.z); m.w = fmaxf(m.w, w.w);
      }
      ushort4 o = { f2bf(m.x), f2bf(m.y), f2bf(m.z), f2bf(m.w) };
      *(ushort4*)(g_segb + ((size_t)b * 9 + n) * 128 + dq) = o;
    }
  } else if (bx < SEGB + OBSB) {
    size_t i = ((size_t)(bx - SEGB) * 256 + tid) * 8;
    float f[8]; load8f(obs + i, f);
    *(uint4*)(g_obsb + i) = pack8(f);
  } else if (bx < SEGB + OBSB + ISOB) {
    size_t i = ((size_t)(bx - SEGB - OBSB) * 256 + tid) * 8;
    float f[8]; load8f(iso + i, f);
    *(uint4*)(g_isob + i) = pack8(f);
  } else if (bx < SEGB + OBSB + 2 * ISOB) {
    size_t i = ((size_t)(bx - SEGB - OBSB - ISOB) * 256 + tid) * 8;
    float f[8]; load8f(isof + i, f);
    *(uint4*)(g_isofb + i) = pack8(f);
  } else {
    // weight transpose+cast: f32 in[K][N] -> bf16 out[N][K]
    bx -= SEGB + OBSB + 2 * ISOB;
    const float* in; u16* out; int K, N, row_off = 0, k0, n0;
    if (bx < 80)       { in = W1;  out = g_W1t;  K = 320; N = 256; k0 = (bx % 10) * 32; n0 = (bx / 10) * 32; }
    else if (bx < 144) { bx -= 80;  in = W2;  out = g_W2t;  K = 256; N = 256; k0 = (bx & 7) * 32; n0 = (bx >> 3) * 32; }
    else if (bx < 208) { bx -= 144; in = Wr;  out = g_Rt;   K = 256; N = 256; k0 = (bx & 7) * 32; n0 = (bx >> 3) * 32; }
    else if (bx < 216) { bx -= 208; in = Wm;  out = g_Wcat; K = 256; N = 32;  k0 = bx * 32; n0 = 0; }
    else               { bx -= 216; in = Wsg; out = g_Wcat; K = 256; N = 32;  k0 = bx * 32; n0 = 0; row_off = 32; }
    int c = tid & 31, r0 = tid >> 5;
    #pragma unroll
    for (int i = 0; i < 4; i++) {
      int r = r0 + i * 8;
      tile[r][c] = f2bf(in[(size_t)(k0 + r) * N + (n0 + c)]);
    }
    __syncthreads();
    #pragma unroll
    for (int i = 0; i < 4; i++) {
      int r = r0 + i * 8;
      out[(size_t)(n0 + r + row_off) * K + (k0 + c)] = tile[c][r];
    }
  }
}

// ---------------- fused node + rho + heads kernel ------------------------------
// grid = 256 (1 block/CU). Block: W1/W2 fragments resident in regs; loops over
// 2 batch-tiles of 16 rows; per tile: 12 nodes -> pool in regs -> GEMM3 -> heads.
__global__ __launch_bounds__(256, 1)
void node_kernel(const float* __restrict__ b1, const float* __restrict__ b2,
                 const float* __restrict__ br, const float* __restrict__ bm,
                 const float* __restrict__ bs, float* __restrict__ out) {
  __shared__ __attribute__((aligned(16))) u16 Ht[16][264];  // 16x256, pad->2-way
  const int tid = threadIdx.x;
  const int wave = tid >> 6, lane = tid & 63;
  const int nw = wave * 64, lrow = lane & 15, quad = lane >> 4;

  // ---- resident B fragments: W1^T 40 VGPR-quads (160), W2^T 32 (128) -------
  bf16x8 w1f[10][4];   // [kc][nb]
  #pragma unroll
  for (int kc = 0; kc < 10; kc++)
    #pragma unroll
    for (int nb = 0; nb < 4; nb++)
      w1f[kc][nb] = *(const bf16x8*)(g_W1t + (size_t)(nw + nb * 16 + lrow) * 320
                                     + kc * 32 + quad * 8);
  bf16x8 w2f[8][4];
  #pragma unroll
  for (int kc = 0; kc < 8; kc++)
    #pragma unroll
    for (int nb = 0; nb < 4; nb++)
      w2f[kc][nb] = *(const bf16x8*)(g_W2t + (size_t)(nw + nb * 16 + lrow) * 256
                                     + kc * 32 + quad * 8);

  float bv1[4], bv2[4];
  #pragma unroll
  for (int nb = 0; nb < 4; nb++) {
    int col = nw + nb * 16 + lrow;
    bv1[nb] = b1[col]; bv2[nb] = b2[col];
  }

  const f32x4 vzero = {0.f, 0.f, 0.f, 0.f};

  for (int t = 0; t < 2; t++) {
    const int b0 = (blockIdx.x * 2 + t) * 16;
    const size_t ar = (size_t)(b0 + lrow);          // A-row this lane reads
    const u16* obsrow = g_obsb + ar * OBSW;

    f32x4 pool[4];
    #pragma unroll
    for (int b = 0; b < 4; b++) pool[b] = vzero;

    for (int n = 0; n < 12; n++) {
      // srcA + kk valid for kk in [64,192); srcS + kk valid for kk in [192,320)
      const u16* srcA = (n < 9) ? obsrow + n * 128
                                : g_isob  + (ar * 3 + (n - 9)) * 128 - 64;
      const u16* srcS = (n < 9) ? g_segb  + (ar * 9 + n) * 128 - 192
                                : g_isofb + (ar * 3 + (n - 9)) * 128 - 192;
      // A fragments for this node (10 x 16B, L1/L3-resident)
      bf16x8 a[10];
      #pragma unroll
      for (int kc = 0; kc < 10; kc++) {
        const int kk = kc * 32 + quad * 8;
        const u16* ap = (kc < 2) ? obsrow + kk : (kc < 6) ? srcA + kk : srcS + kk;
        a[kc] = *(const bf16x8*)ap;
      }

      f32x4 acc[4];
      #pragma unroll
      for (int b = 0; b < 4; b++) acc[b] = vzero;
      // ---- GEMM1: K=320, B resident in regs — zero memory ops --------------
      #pragma unroll
      for (int kc = 0; kc < 10; kc++)
        #pragma unroll
        for (int nb = 0; nb < 4; nb++)
          acc[nb] = __builtin_amdgcn_mfma_f32_16x16x32_bf16(a[kc], w1f[kc][nb],
                                                            acc[nb], 0, 0, 0);

      __syncthreads();   // prior Ht readers done (GEMM2(n-1) / heads(t-1))
      // epilogue 1: Ht = bf16(relu(acc + b1))  (D: row=quad*4+i, col)
      #pragma unroll
      for (int nb = 0; nb < 4; nb++) {
        int col = nw + nb * 16 + lrow;
        #pragma unroll
        for (int i = 0; i < 4; i++)
          Ht[quad * 4 + i][col] = f2bf(fmaxf(acc[nb][i] + bv1[nb], 0.f));
      }
      __syncthreads();   // Ht(n) ready

      #pragma unroll
      for (int b = 0; b < 4; b++) acc[b] = vzero;
      // ---- GEMM2: K=256, A from Ht (LDS), B resident in regs ---------------
      #pragma unroll
      for (int kc = 0; kc < 8; kc++) {
        const int kk = kc * 32 + quad * 8;
        bf16x8 af = *(const bf16x8*)(&Ht[lrow][kk]);
        #pragma unroll
        for (int nb = 0; nb < 4; nb++)
          acc[nb] = __builtin_amdgcn_mfma_f32_16x16x32_bf16(af, w2f[kc][nb],
                                                            acc[nb], 0, 0, 0);
      }
      // epilogue 2: pool += relu(acc + b2)
      #pragma unroll
      for (int nb = 0; nb < 4; nb++)
        #pragma unroll
        for (int i = 0; i < 4; i++)
          pool[nb][i] += fmaxf(acc[nb][i] + bv2[nb], 0.f);
    }

    // ---- rho: pooled -> bf16 A-tile (reuse Ht) -> GEMM3(relu,br) -----------
    __syncthreads();   // last GEMM2's Ht reads done
    #pragma unroll
    for (int nb = 0; nb < 4; nb++) {
      int col = nw + nb * 16 + lrow;
      #pragma unroll
      for (int i = 0; i < 4; i++)
        Ht[quad * 4 + i][col] = f2bf(pool[nb][i]);
    }
    __syncthreads();

    f32x4 acc[4];
    #pragma unroll
    for (int b = 0; b < 4; b++) acc[b] = vzero;
    #pragma unroll
    for (int kc = 0; kc < 8; kc++) {
      const int kk = kc * 32 + quad * 8;
      bf16x8 af = *(const bf16x8*)(&Ht[lrow][kk]);
      #pragma unroll
      for (int nb = 0; nb < 4; nb++) {
        bf16x8 bq = *(const bf16x8*)(g_Rt + (size_t)(nw + nb * 16 + lrow) * 256 + kk);
        acc[nb] = __builtin_amdgcn_mfma_f32_16x16x32_bf16(af, bq, acc[nb], 0, 0, 0);
      }
    }
    __syncthreads();   // Ht reads done
    #pragma unroll
    for (int nb = 0; nb < 4; nb++) {
      int col = nw + nb * 16 + lrow;
      float bv = br[col];
      #pragma unroll
      for (int i = 0; i < 4; i++)
        Ht[quad * 4 + i][col] = f2bf(fmaxf(acc[nb][i] + bv, 0.f));
    }
    __syncthreads();   // r visible

    // ---- heads: N=64 (mean|log_std); wave w owns 16-col tile w -------------
    f32x4 acc2 = vzero;
    #pragma unroll
    for (int kc = 0; kc < 8; kc++) {
      const int kk = kc * 32 + quad * 8;
      bf16x8 af = *(const bf16x8*)(&Ht[lrow][kk]);
      bf16x8 bq = *(const bf16x8*)(g_Wcat + (size_t)(wave * 16 + lrow) * 256 + kk);
      acc2 = __builtin_amdgcn_mfma_f32_16x16x32_bf16(af, bq, acc2, 0, 0, 0);
    }
    int j = wave * 16 + lrow;
    #pragma unroll
    for (int i = 0; i < 4; i++) {
      int b = b0 + quad * 4 + i;
      if (j < 32) {
        out[(size_t)b * 32 + j] = acc2[i] + bm[j];
      } else {
        float v = acc2[i] + bs[j - 32];
        v = fminf(fmaxf(v, -20.f), 2.f);
        out[(size_t)Bsz * 32 + (size_t)b * 32 + (j - 32)] = v;
      }
    }
    // next tile's first epilogue-1 barrier covers these Ht reads
  }
}

extern "C" void kernel_launch(void* const* d_in, const int* in_sizes, int n_in,
                              void* d_out, int out_size, void* d_ws, size_t ws_size,
                              hipStream_t stream) {
  const float* obs  = (const float*)d_in[0];
  const float* ef   = (const float*)d_in[1];
  // d_in[2] = edges_to (int32): tile(arange(9),8) -> edge e feeds node e%9
  const float* iso  = (const float*)d_in[3];
  const float* isof = (const float*)d_in[4];
  const float* W1   = (const float*)d_in[5];
  const float* b1   = (const float*)d_in[6];
  const float* W2   = (const float*)d_in[7];
  const float* b2   = (const float*)d_in[8];
  const float* Wr   = (const float*)d_in[9];
  const float* br   = (const float*)d_in[10];
  const float* Wm   = (const float*)d_in[11];
  const float* bm   = (const float*)d_in[12];
  const float* Wsg  = (const float*)d_in[13];
  const float* bs   = (const float*)d_in[14];
  float* out = (float*)d_out;
  (void)d_ws; (void)ws_size;

  prep<<<SEGB + OBSB + 2 * ISOB + 224, 256, 0, stream>>>(
      obs, ef, iso, isof, W1, W2, Wr, Wm, Wsg);
  node_kernel<<<256, 256, 0, stream>>>(b1, b2, br, bm, bs, out);
}

// Round 6
// 490.252 us; speedup vs baseline: 1.4228x; 1.1489x over previous
//
#include <hip/hip_runtime.h>
#include <hip/hip_bf16.h>
#include <stdint.h>

// GnnActor fused deepset actor. INPUTS/OUTPUTS ARE FLOAT32 (reference dtype).
// v6 (single fused streaming kernel) — resubmission; round-5 bench never ran
// (GPU acquisition timeout), so this is unchanged to get its measurement.
//  - prep kernel ELIMINATED. node_kernel streams ef directly: loads for node
//    n+1 are issued before GEMM1(n) (T14 async split), max-reduced and written
//    to the As LDS tile after the Ht barrier. Compute (MFMA w/ register-
//    resident weights) hides under the 302 MB edge stream -> BW-bound kernel.
//  - 512-thread blocks (8 waves, 32 output cols each): W1^T(80)+W2^T(64)=144
//    VGPR resident per wave -> fits 2 waves/SIMD (launch_bounds(512,2)).
//    Grid 512 = 1 block/CU, 16 batch rows per block.
//  - obs/iso/isof read f32 directly (cast in-register); all bf16 intermediate
//    arrays + g_pool2 deleted (~52 MB .bss -> 0.6 MB weights only).
//  - 2 barriers per node; rho + heads fused per block as before.
// Scratch in module __device__ arrays (no d_ws use; graph-safe).

#define Bsz   8192
#define OBSW  1216      // 64 + 9*128
#define NH    256

typedef unsigned short u16;
typedef unsigned int   u32;

using bf16x8 = __attribute__((ext_vector_type(8))) short;
using f32x4  = __attribute__((ext_vector_type(4))) float;

// ---- module-scope scratch (~0.6 MB .bss) ----
__device__ __attribute__((aligned(16))) u16 g_W1t[256 * 320];   // bf16(W1)^T
__device__ __attribute__((aligned(16))) u16 g_W2t[256 * 256];   // bf16(W2)^T
__device__ __attribute__((aligned(16))) u16 g_Rt [256 * 256];   // bf16(Wrho)^T
__device__ __attribute__((aligned(16))) u16 g_Wcat[64 * 256];   // [Wm^T ; Ws^T]

__device__ __forceinline__ u16 f2bf(float f) {
  union { float f; u32 i; } v; v.f = f;
  u32 x = v.i;
  x += 0x7fffu + ((x >> 16) & 1u);   // RNE; values here are finite
  return (u16)(x >> 16);
}
__device__ __forceinline__ ushort4 pack4(float4 f) {
  ushort4 o = { f2bf(f.x), f2bf(f.y), f2bf(f.z), f2bf(f.w) };
  return o;
}

// ---------------- weight transpose+cast (one small launch) ---------------------
// f32 in[K][N] -> bf16 out[N][K]; 224 blocks cover W1|W2|Wr|Wm|Ws.
__global__ __launch_bounds__(256)
void transpose_all(const float* __restrict__ W1, const float* __restrict__ W2,
                   const float* __restrict__ Wr, const float* __restrict__ Wm,
                   const float* __restrict__ Wsg) {
  __shared__ u16 tile[32][33];
  int bx = blockIdx.x;
  const float* in; u16* out; int K, N, row_off = 0, k0, n0;
  if (bx < 80)       { in = W1;  out = g_W1t;  K = 320; N = 256; k0 = (bx % 10) * 32; n0 = (bx / 10) * 32; }
  else if (bx < 144) { bx -= 80;  in = W2;  out = g_W2t;  K = 256; N = 256; k0 = (bx & 7) * 32; n0 = (bx >> 3) * 32; }
  else if (bx < 208) { bx -= 144; in = Wr;  out = g_Rt;   K = 256; N = 256; k0 = (bx & 7) * 32; n0 = (bx >> 3) * 32; }
  else if (bx < 216) { bx -= 208; in = Wm;  out = g_Wcat; K = 256; N = 32;  k0 = bx * 32; n0 = 0; }
  else               { bx -= 216; in = Wsg; out = g_Wcat; K = 256; N = 32;  k0 = bx * 32; n0 = 0; row_off = 32; }
  int c = threadIdx.x & 31, r0 = threadIdx.x >> 5;
  #pragma unroll
  for (int i = 0; i < 4; i++) {
    int r = r0 + i * 8;
    tile[r][c] = f2bf(in[(size_t)(k0 + r) * N + (n0 + c)]);
  }
  __syncthreads();
  #pragma unroll
  for (int i = 0; i < 4; i++) {
    int r = r0 + i * 8;
    out[(size_t)(n0 + r + row_off) * K + (k0 + c)] = tile[c][r];
  }
}

// ---------------- fused stream + node + rho + heads kernel ---------------------
// grid = Bsz/16 = 512 (1 block/CU), 512 threads (8 waves).
__global__ __launch_bounds__(512, 2)
void node_kernel(const float* __restrict__ obs, const float* __restrict__ ef,
                 const float* __restrict__ iso, const float* __restrict__ isof,
                 const float* __restrict__ b1, const float* __restrict__ b2,
                 const float* __restrict__ br, const float* __restrict__ bm,
                 const float* __restrict__ bs, float* __restrict__ out) {
  __shared__ __attribute__((aligned(16))) u16 As[16][328];  // 16x320 A-tile
  __shared__ __attribute__((aligned(16))) u16 Ht[16][264];  // 16x256 hidden
  const int b0 = blockIdx.x * 16;
  const int tid = threadIdx.x;
  const int wave = tid >> 6, lane = tid & 63;
  const int w32 = wave * 32, lrow = lane & 15, quad = lane >> 4;
  const int sr = tid >> 5, sc = tid & 31, dq4 = sc * 4;   // staging map
  const size_t ar = (size_t)(b0 + sr);                    // staging row

  // ---- resident B fragments: W1^T 80 VGPR, W2^T 64 VGPR (per wave) ---------
  bf16x8 w1f[10][2];   // [kc][nb]
  #pragma unroll
  for (int kc = 0; kc < 10; kc++)
    #pragma unroll
    for (int nb = 0; nb < 2; nb++)
      w1f[kc][nb] = *(const bf16x8*)(g_W1t + (size_t)(w32 + nb * 16 + lrow) * 320
                                     + kc * 32 + quad * 8);
  bf16x8 w2f[8][2];
  #pragma unroll
  for (int kc = 0; kc < 8; kc++)
    #pragma unroll
    for (int nb = 0; nb < 2; nb++)
      w2f[kc][nb] = *(const bf16x8*)(g_W2t + (size_t)(w32 + nb * 16 + lrow) * 256
                                     + kc * 32 + quad * 8);

  float bv1[2], bv2[2];
  #pragma unroll
  for (int nb = 0; nb < 2; nb++) {
    int col = w32 + nb * 16 + lrow;
    bv1[nb] = b1[col]; bv2[nb] = b2[col];
  }

  // ---- prologue: stage As(node 0) [body | obj | segmax] --------------------
  {
    if (sc < 16) {   // body cols 0..63 (dq4 < 64)
      float4 fb = *(const float4*)(obs + ar * OBSW + dq4);
      *(ushort4*)(&As[sr][dq4]) = pack4(fb);
    }
    float4 pa = *(const float4*)(obs + ar * OBSW + 64 + dq4);   // node 0 obj
    const float* base = ef + (ar * 72 + 0) * 128 + dq4;         // node 0 edges
    float4 m = *(const float4*)base;
    #pragma unroll
    for (int j = 1; j < 8; j++) {
      float4 w = *(const float4*)(base + (size_t)j * 1152);
      m.x = fmaxf(m.x, w.x); m.y = fmaxf(m.y, w.y);
      m.z = fmaxf(m.z, w.z); m.w = fmaxf(m.w, w.w);
    }
    *(ushort4*)(&As[sr][64  + dq4]) = pack4(pa);
    *(ushort4*)(&As[sr][192 + dq4]) = pack4(m);
  }
  __syncthreads();   // As(0) ready

  const f32x4 vzero = {0.f, 0.f, 0.f, 0.f};
  f32x4 pool[2] = {vzero, vzero};

  for (int n = 0; n < 12; n++) {
    // ---- issue loads for node n+1 (consumed after the Ht barrier) ----------
    const int n1 = n + 1;
    float4 pe[8]; float4 pa; float4 ps;
    if (n1 < 12) {
      if (n1 < 9) {
        pa = *(const float4*)(obs + ar * OBSW + 64 + (size_t)n1 * 128 + dq4);
        const float* base = ef + (ar * 72 + n1) * 128 + dq4;
        #pragma unroll
        for (int j = 0; j < 8; j++)
          pe[j] = *(const float4*)(base + (size_t)j * 1152);
      } else {
        pa = *(const float4*)(iso  + (ar * 3 + (n1 - 9)) * 128 + dq4);
        ps = *(const float4*)(isof + (ar * 3 + (n1 - 9)) * 128 + dq4);
      }
    }

    // ---- GEMM1: K=320, A from As (LDS), B resident — no memory stalls ------
    f32x4 acc[2] = {vzero, vzero};
    #pragma unroll
    for (int kc = 0; kc < 10; kc++) {
      bf16x8 af = *(const bf16x8*)(&As[lrow][kc * 32 + quad * 8]);
      #pragma unroll
      for (int nb = 0; nb < 2; nb++)
        acc[nb] = __builtin_amdgcn_mfma_f32_16x16x32_bf16(af, w1f[kc][nb],
                                                          acc[nb], 0, 0, 0);
    }
    // epilogue 1: Ht = bf16(relu(acc + b1))  (safe: Ht readers done at S2(n-1))
    #pragma unroll
    for (int nb = 0; nb < 2; nb++) {
      int col = w32 + nb * 16 + lrow;
      #pragma unroll
      for (int i = 0; i < 4; i++)
        Ht[quad * 4 + i][col] = f2bf(fmaxf(acc[nb][i] + bv1[nb], 0.f));
    }
    __syncthreads();   // S1: Ht(n) ready; As(n) GEMM1 reads retired

    // ---- reduce prefetched data -> stage As(n+1) ---------------------------
    if (n1 < 12) {
      *(ushort4*)(&As[sr][64 + dq4]) = pack4(pa);
      if (n1 < 9) {
        float4 m = pe[0];
        #pragma unroll
        for (int j = 1; j < 8; j++) {
          m.x = fmaxf(m.x, pe[j].x); m.y = fmaxf(m.y, pe[j].y);
          m.z = fmaxf(m.z, pe[j].z); m.w = fmaxf(m.w, pe[j].w);
        }
        *(ushort4*)(&As[sr][192 + dq4]) = pack4(m);
      } else {
        *(ushort4*)(&As[sr][192 + dq4]) = pack4(ps);
      }
    }

    // ---- GEMM2: K=256, A from Ht (LDS), B resident -------------------------
    f32x4 acc2[2] = {vzero, vzero};
    #pragma unroll
    for (int kc = 0; kc < 8; kc++) {
      bf16x8 af = *(const bf16x8*)(&Ht[lrow][kc * 32 + quad * 8]);
      #pragma unroll
      for (int nb = 0; nb < 2; nb++)
        acc2[nb] = __builtin_amdgcn_mfma_f32_16x16x32_bf16(af, w2f[kc][nb],
                                                           acc2[nb], 0, 0, 0);
    }
    // epilogue 2: pool += relu(acc + b2)
    #pragma unroll
    for (int nb = 0; nb < 2; nb++)
      #pragma unroll
      for (int i = 0; i < 4; i++)
        pool[nb][i] += fmaxf(acc2[nb][i] + bv2[nb], 0.f);
    __syncthreads();   // S2: As(n+1) visible; Ht(n) reads done
  }

  // ---- rho: pooled -> bf16 A-tile (reuse Ht) -> GEMM3(relu,br) -------------
  #pragma unroll
  for (int nb = 0; nb < 2; nb++) {
    int col = w32 + nb * 16 + lrow;
    #pragma unroll
    for (int i = 0; i < 4; i++)
      Ht[quad * 4 + i][col] = f2bf(pool[nb][i]);
  }
  __syncthreads();

  f32x4 acc3[2] = {vzero, vzero};
  #pragma unroll
  for (int kc = 0; kc < 8; kc++) {
    bf16x8 af = *(const bf16x8*)(&Ht[lrow][kc * 32 + quad * 8]);
    #pragma unroll
    for (int nb = 0; nb < 2; nb++) {
      bf16x8 bq = *(const bf16x8*)(g_Rt + (size_t)(w32 + nb * 16 + lrow) * 256
                                   + kc * 32 + quad * 8);
      acc3[nb] = __builtin_amdgcn_mfma_f32_16x16x32_bf16(af, bq, acc3[nb], 0, 0, 0);
    }
  }
  __syncthreads();   // Ht reads done
  #pragma unroll
  for (int nb = 0; nb < 2; nb++) {
    int col = w32 + nb * 16 + lrow;
    float bv = br[col];
    #pragma unroll
    for (int i = 0; i < 4; i++)
      Ht[quad * 4 + i][col] = f2bf(fmaxf(acc3[nb][i] + bv, 0.f));
  }
  __syncthreads();   // r visible

  // ---- heads: N=64 (mean|log_std); waves 0..3 own 16-col tiles -------------
  if (wave < 4) {
    f32x4 acch = vzero;
    #pragma unroll
    for (int kc = 0; kc < 8; kc++) {
      bf16x8 af = *(const bf16x8*)(&Ht[lrow][kc * 32 + quad * 8]);
      bf16x8 bq = *(const bf16x8*)(g_Wcat + (size_t)(wave * 16 + lrow) * 256
                                   + kc * 32 + quad * 8);
      acch = __builtin_amdgcn_mfma_f32_16x16x32_bf16(af, bq, acch, 0, 0, 0);
    }
    int j = wave * 16 + lrow;
    #pragma unroll
    for (int i = 0; i < 4; i++) {
      int b = b0 + quad * 4 + i;
      if (j < 32) {
        out[(size_t)b * 32 + j] = acch[i] + bm[j];
      } else {
        float v = acch[i] + bs[j - 32];
        v = fminf(fmaxf(v, -20.f), 2.f);
        out[(size_t)Bsz * 32 + (size_t)b * 32 + (j - 32)] = v;
      }
    }
  }
}

extern "C" void kernel_launch(void* const* d_in, const int* in_sizes, int n_in,
                              void* d_out, int out_size, void* d_ws, size_t ws_size,
                              hipStream_t stream) {
  const float* obs  = (const float*)d_in[0];
  const float* ef   = (const float*)d_in[1];
  // d_in[2] = edges_to (int32): tile(arange(9),8) -> edge e feeds node e%9
  const float* iso  = (const float*)d_in[3];
  const float* isof = (const float*)d_in[4];
  const float* W1   = (const float*)d_in[5];
  const float* b1   = (const float*)d_in[6];
  const float* W2   = (const float*)d_in[7];
  const float* b2   = (const float*)d_in[8];
  const float* Wr   = (const float*)d_in[9];
  const float* br   = (const float*)d_in[10];
  const float* Wm   = (const float*)d_in[11];
  const float* bm   = (const float*)d_in[12];
  const float* Wsg  = (const float*)d_in[13];
  const float* bs   = (const float*)d_in[14];
  float* out = (float*)d_out;
  (void)d_ws; (void)ws_size;

  transpose_all<<<224, 256, 0, stream>>>(W1, W2, Wr, Wm, Wsg);
  node_kernel<<<Bsz / 16, 512, 0, stream>>>(obs, ef, iso, isof,
                                            b1, b2, br, bm, bs, out);
}